// Round 3
// baseline (203.968 us; speedup 1.0000x reference)
//
#include <hip/hip_runtime.h>

// Dynamic voxelization: coors[d, i] = valid ? floor((p[i,d]-mn[d])/vs[d]) : -1
// Memory-bound streaming: 128 MB read + 96 MB write, no reuse. Floor ~36 us
// at 6.3 TB/s copy ceiling; two harness restore fills (~155 us) ride on top.
//
// Round-1 post-mortem: 4-consecutive-points/thread made loads stride-64B per
// instruction (64 line requests/instr vs 16) -> kernel ~49 -> ~58 us. REVERTED.
// Round-2 post-mortem: strided-chunk (block owns 1024 pts, thread t handles
// {t,+256,+512,+768}) restored full coalescing + 4x MLP -> kernel ~43 us
// (5.2 TB/s). Best so far.
//
// Round-3 change: PLAIN stores (drop NT hint on stores only). NT stores
// bypass L2/L3 and force the 96 MB write stream to HBM inside the kernel
// window. Plain stores let the 256 MB Infinity Cache absorb the entire
// output at cache-ack speed with lazy write-back, leaving in-window HBM
// traffic read-dominated. Loads keep NT (read-once; don't pollute L3, keep
// it free for write absorption).
// Numerics must match np reference: fp32 sub, IEEE fp32 div, floorf, trunc
// (reciprocal-multiply risks a validity flip at grid boundary -> absmax 1600).

typedef float fx4 __attribute__((ext_vector_type(4)));

#define VS_X 0.05f
#define VS_Y 0.05f
#define VS_Z 0.1f
#define MN_X 0.0f
#define MN_Y -40.0f
#define MN_Z -3.0f
#define GX 1408
#define GY 1600
#define GZ 40

#define PTS_PER_BLOCK 1024  // 256 threads x 4 points, stride-256 within block

__device__ __forceinline__ void voxel_one(const fx4 p, int& vx, int& vy, int& vz) {
    int cx = (int)floorf((p.x - MN_X) / VS_X);
    int cy = (int)floorf((p.y - MN_Y) / VS_Y);
    int cz = (int)floorf((p.z - MN_Z) / VS_Z);
    bool valid = (cx >= 0) & (cx < GX) & (cy >= 0) & (cy < GY) & (cz >= 0) & (cz < GZ);
    vx = valid ? cx : -1;
    vy = valid ? cy : -1;
    vz = valid ? cz : -1;
}

__global__ __launch_bounds__(256) void voxelize_kernel(
    const fx4* __restrict__ points, int* __restrict__ out, int n) {
    int base = blockIdx.x * PTS_PER_BLOCK + threadIdx.x;

    if (base + 768 < n) {
        // Full block: all 4 strided points in range. 4 independent NT loads.
        fx4 p0 = __builtin_nontemporal_load(&points[base]);
        fx4 p1 = __builtin_nontemporal_load(&points[base + 256]);
        fx4 p2 = __builtin_nontemporal_load(&points[base + 512]);
        fx4 p3 = __builtin_nontemporal_load(&points[base + 768]);

        int x0, y0, z0, x1, y1, z1, x2, y2, z2, x3, y3, z3;
        voxel_one(p0, x0, y0, z0);
        voxel_one(p1, x1, y1, z1);
        voxel_one(p2, x2, y2, z2);
        voxel_one(p3, x3, y3, z3);

        int* ox = out;
        int* oy = out + n;
        int* oz = out + 2 * n;
        ox[base]       = x0;
        ox[base + 256] = x1;
        ox[base + 512] = x2;
        ox[base + 768] = x3;
        oy[base]       = y0;
        oy[base + 256] = y1;
        oy[base + 512] = y2;
        oy[base + 768] = y3;
        oz[base]       = z0;
        oz[base + 256] = z1;
        oz[base + 512] = z2;
        oz[base + 768] = z3;
    } else {
        // Tail block: per-point guard.
        #pragma unroll
        for (int k = 0; k < 4; ++k) {
            int i = base + k * 256;
            if (i < n) {
                fx4 p = __builtin_nontemporal_load(&points[i]);
                int vx, vy, vz;
                voxel_one(p, vx, vy, vz);
                out[i]         = vx;
                out[n + i]     = vy;
                out[2 * n + i] = vz;
            }
        }
    }
}

extern "C" void kernel_launch(void* const* d_in, const int* in_sizes, int n_in,
                              void* d_out, int out_size, void* d_ws, size_t ws_size,
                              hipStream_t stream) {
    const fx4* points = (const fx4*)d_in[0];
    int* out = (int*)d_out;
    int n = in_sizes[0] / 4;  // points is (N, 4) flat

    int block = 256;
    int grid = (n + PTS_PER_BLOCK - 1) / PTS_PER_BLOCK;
    voxelize_kernel<<<grid, block, 0, stream>>>(points, out, n);
}

// Round 4
// 201.906 us; speedup vs baseline: 1.0102x; 1.0102x over previous
//
#include <hip/hip_runtime.h>

// Dynamic voxelization: coors[d, i] = valid ? floor((p[i,d]-mn[d])/vs[d]) : -1
// Memory-bound streaming: 128 MB read + 96 MB write, no reuse. Two harness
// restore fills (~155 us) ride on top of every measurement.
//
// Ladder: R0 1pt/thread NT: kernel ~49us. R1 4-consecutive/thread: ~58us
// (stride-64B lanes broke coalescing) REVERTED. R2 strided-chunk x4
// ({t,+256,+512,+768}, all instrs lane-contiguous): ~43us, 5.2 TB/s. BEST.
// R3 plain stores: ~48us — write-back contends with read stream; NT
// no-allocate stores are RIGHT for this kernel. REVERTED.
//
// Round-4 change: 8 points/thread (PTS_PER_BLOCK 2048), same strided-chunk
// layout. 8 independent NT loads in flight per thread (2x MLP vs R2) to
// close the last latency-hiding gap toward the ~5.5-5.8 TB/s mixed-stream
// ceiling. Stores: scalar dword NT, lane-contiguous (full 64B lines/wave).
// Numerics must match np reference: fp32 sub, IEEE fp32 div, floorf, trunc
// (reciprocal-multiply risks a validity flip at grid boundary -> absmax 1600).

typedef float fx4 __attribute__((ext_vector_type(4)));

#define VS_X 0.05f
#define VS_Y 0.05f
#define VS_Z 0.1f
#define MN_X 0.0f
#define MN_Y -40.0f
#define MN_Z -3.0f
#define GX 1408
#define GY 1600
#define GZ 40

#define UNROLL 8
#define PTS_PER_BLOCK 2048  // 256 threads x 8 points, stride-256 within block

__device__ __forceinline__ void voxel_one(const fx4 p, int& vx, int& vy, int& vz) {
    int cx = (int)floorf((p.x - MN_X) / VS_X);
    int cy = (int)floorf((p.y - MN_Y) / VS_Y);
    int cz = (int)floorf((p.z - MN_Z) / VS_Z);
    bool valid = (cx >= 0) & (cx < GX) & (cy >= 0) & (cy < GY) & (cz >= 0) & (cz < GZ);
    vx = valid ? cx : -1;
    vy = valid ? cy : -1;
    vz = valid ? cz : -1;
}

__global__ __launch_bounds__(256) void voxelize_kernel(
    const fx4* __restrict__ points, int* __restrict__ out, int n) {
    int base = blockIdx.x * PTS_PER_BLOCK + threadIdx.x;

    if (base + (UNROLL - 1) * 256 < n) {
        // Full block: all 8 strided points in range. 8 independent NT loads.
        fx4 p[UNROLL];
        #pragma unroll
        for (int k = 0; k < UNROLL; ++k)
            p[k] = __builtin_nontemporal_load(&points[base + k * 256]);

        int vx[UNROLL], vy[UNROLL], vz[UNROLL];
        #pragma unroll
        for (int k = 0; k < UNROLL; ++k)
            voxel_one(p[k], vx[k], vy[k], vz[k]);

        int* ox = out;
        int* oy = out + n;
        int* oz = out + 2 * n;
        #pragma unroll
        for (int k = 0; k < UNROLL; ++k)
            __builtin_nontemporal_store(vx[k], ox + base + k * 256);
        #pragma unroll
        for (int k = 0; k < UNROLL; ++k)
            __builtin_nontemporal_store(vy[k], oy + base + k * 256);
        #pragma unroll
        for (int k = 0; k < UNROLL; ++k)
            __builtin_nontemporal_store(vz[k], oz + base + k * 256);
    } else {
        // Tail block: per-point guard.
        #pragma unroll
        for (int k = 0; k < UNROLL; ++k) {
            int i = base + k * 256;
            if (i < n) {
                fx4 q = __builtin_nontemporal_load(&points[i]);
                int vx, vy, vz;
                voxel_one(q, vx, vy, vz);
                __builtin_nontemporal_store(vx, out + i);
                __builtin_nontemporal_store(vy, out + n + i);
                __builtin_nontemporal_store(vz, out + 2 * n + i);
            }
        }
    }
}

extern "C" void kernel_launch(void* const* d_in, const int* in_sizes, int n_in,
                              void* d_out, int out_size, void* d_ws, size_t ws_size,
                              hipStream_t stream) {
    const fx4* points = (const fx4*)d_in[0];
    int* out = (int*)d_out;
    int n = in_sizes[0] / 4;  // points is (N, 4) flat

    int block = 256;
    int grid = (n + PTS_PER_BLOCK - 1) / PTS_PER_BLOCK;
    voxelize_kernel<<<grid, block, 0, stream>>>(points, out, n);
}

// Round 5
// 198.362 us; speedup vs baseline: 1.0283x; 1.0179x over previous
//
#include <hip/hip_runtime.h>

// Dynamic voxelization: coors[d, i] = valid ? floor((p[i,d]-mn[d])/vs[d]) : -1
// Memory-bound streaming: 128 MB read + 96 MB write, no reuse. Two harness
// restore fills (~151 us at 6.7 TB/s pure-write) ride on top of every
// measurement; kernel portion ~43 us = 5.2 TB/s mixed read+write.
//
// Ladder (kernel-portion us, dur_us = kernel + ~151-155 fill):
//   R0 1pt/thread NT:            ~49us
//   R1 4-consecutive/thread:     ~58us  (stride-64B lanes broke per-instr
//                                        coalescing) REVERTED
//   R2 strided-chunk x4:         ~43us  BEST (this kernel)
//   R3 plain stores:             ~48us  (write-back contends with reads;
//                                        NT no-allocate is right) REVERTED
//   R4 strided-chunk x8:         ~50us  (too-deep queues + half the blocks;
//                                        MLP sweet spot is 4) REVERTED
//
// Structure: block owns 1024 consecutive points; thread t handles
// {t, t+256, t+512, t+768}. Every load/store instr is lane-contiguous
// (loads 16 B/lane = 1 KB/wave/instr, whole 64B lines consumed -> NT-safe;
// stores 4 B/lane = 256 B/wave/instr). 4 independent loads in flight/thread.
// Numerics must match np reference: fp32 sub, IEEE fp32 div, floorf, trunc
// (reciprocal-multiply risks a validity flip at grid boundary -> absmax 1600).

typedef float fx4 __attribute__((ext_vector_type(4)));

#define VS_X 0.05f
#define VS_Y 0.05f
#define VS_Z 0.1f
#define MN_X 0.0f
#define MN_Y -40.0f
#define MN_Z -3.0f
#define GX 1408
#define GY 1600
#define GZ 40

#define PTS_PER_BLOCK 1024  // 256 threads x 4 points, stride-256 within block

__device__ __forceinline__ void voxel_one(const fx4 p, int& vx, int& vy, int& vz) {
    int cx = (int)floorf((p.x - MN_X) / VS_X);
    int cy = (int)floorf((p.y - MN_Y) / VS_Y);
    int cz = (int)floorf((p.z - MN_Z) / VS_Z);
    bool valid = (cx >= 0) & (cx < GX) & (cy >= 0) & (cy < GY) & (cz >= 0) & (cz < GZ);
    vx = valid ? cx : -1;
    vy = valid ? cy : -1;
    vz = valid ? cz : -1;
}

__global__ __launch_bounds__(256) void voxelize_kernel(
    const fx4* __restrict__ points, int* __restrict__ out, int n) {
    int base = blockIdx.x * PTS_PER_BLOCK + threadIdx.x;

    if (base + 768 < n) {
        // Full block: all 4 strided points in range. 4 independent NT loads.
        fx4 p0 = __builtin_nontemporal_load(&points[base]);
        fx4 p1 = __builtin_nontemporal_load(&points[base + 256]);
        fx4 p2 = __builtin_nontemporal_load(&points[base + 512]);
        fx4 p3 = __builtin_nontemporal_load(&points[base + 768]);

        int x0, y0, z0, x1, y1, z1, x2, y2, z2, x3, y3, z3;
        voxel_one(p0, x0, y0, z0);
        voxel_one(p1, x1, y1, z1);
        voxel_one(p2, x2, y2, z2);
        voxel_one(p3, x3, y3, z3);

        int* ox = out;
        int* oy = out + n;
        int* oz = out + 2 * n;
        __builtin_nontemporal_store(x0, ox + base);
        __builtin_nontemporal_store(x1, ox + base + 256);
        __builtin_nontemporal_store(x2, ox + base + 512);
        __builtin_nontemporal_store(x3, ox + base + 768);
        __builtin_nontemporal_store(y0, oy + base);
        __builtin_nontemporal_store(y1, oy + base + 256);
        __builtin_nontemporal_store(y2, oy + base + 512);
        __builtin_nontemporal_store(y3, oy + base + 768);
        __builtin_nontemporal_store(z0, oz + base);
        __builtin_nontemporal_store(z1, oz + base + 256);
        __builtin_nontemporal_store(z2, oz + base + 512);
        __builtin_nontemporal_store(z3, oz + base + 768);
    } else {
        // Tail block: per-point guard.
        #pragma unroll
        for (int k = 0; k < 4; ++k) {
            int i = base + k * 256;
            if (i < n) {
                fx4 p = __builtin_nontemporal_load(&points[i]);
                int vx, vy, vz;
                voxel_one(p, vx, vy, vz);
                __builtin_nontemporal_store(vx, out + i);
                __builtin_nontemporal_store(vy, out + n + i);
                __builtin_nontemporal_store(vz, out + 2 * n + i);
            }
        }
    }
}

extern "C" void kernel_launch(void* const* d_in, const int* in_sizes, int n_in,
                              void* d_out, int out_size, void* d_ws, size_t ws_size,
                              hipStream_t stream) {
    const fx4* points = (const fx4*)d_in[0];
    int* out = (int*)d_out;
    int n = in_sizes[0] / 4;  // points is (N, 4) flat

    int block = 256;
    int grid = (n + PTS_PER_BLOCK - 1) / PTS_PER_BLOCK;
    voxelize_kernel<<<grid, block, 0, stream>>>(points, out, n);
}